// Round 9
// baseline (608.686 us; speedup 1.0000x reference)
//
#include <hip/hip_runtime.h>

#define NN 2304
#define CC 192
#define NBATCH 16

typedef unsigned short u16;
typedef __bf16 bf16x8 __attribute__((ext_vector_type(8)));
typedef float f32x4 __attribute__((ext_vector_type(4)));
typedef float f32x16 __attribute__((ext_vector_type(16)));

__device__ __forceinline__ u16 bf16bits(float f) {
  union { float f; unsigned u; } v;
  v.f = f;
  unsigned r = v.u + 0x7FFFu + ((v.u >> 16) & 1u);
  return (u16)(r >> 16);
}

// pack two f32 -> u32 of 2 bf16 (RNE), single HW instr
__device__ __forceinline__ uint32_t cvtpk(float lo, float hi) {
  uint32_t d;
  asm("v_cvt_pk_bf16_f32 %0, %1, %2" : "=v"(d) : "v"(lo), "v"(hi));
  return d;
}

// XOR-swizzled LDS element index for a [rows][192] bf16 tile (row stride 192).
__device__ __forceinline__ int swzK(int row, int col) {
  int ch = col >> 3;
  int phys = (ch & ~7) | ((ch ^ row) & 7);
  return row * 192 + (phys << 3) + (col & 7);
}
// Same for [rows][64] bf16 tiles (8 chunks per row).
__device__ __forceinline__ int swz64(int row, int col) {
  int ch = (col >> 3) ^ row;
  return (row << 6) | ((ch & 7) << 3) | (col & 7);
}

// direct global->LDS 16B DMA; dest = wave-uniform base + lane*16
__device__ __forceinline__ void gll16(const u16* g, u16* l) {
  __builtin_amdgcn_global_load_lds(
      (const __attribute__((address_space(1))) u16*)g,
      (__attribute__((address_space(3))) u16*)l, 16, 0, 0);
}

// ---------------------------------------------------------------------------
// Kernel 1: LayerNorm over C, x[b,c,n] (fp32) -> xn[(b*N+n), c] (bf16)
// ---------------------------------------------------------------------------
__global__ __launch_bounds__(256) void ln_kernel(
    const float* __restrict__ x, const float* __restrict__ lnw,
    const float* __restrict__ lnb, u16* __restrict__ xn) {
  __shared__ float xt[192 * 65];
  __shared__ float psum[4][64], psq[4][64];
  __shared__ float mu_s[64], rs_s[64];
  __shared__ float lw_s[192], lb_s[192];
  int t = threadIdx.x;
  int b = blockIdx.y, n0 = blockIdx.x * 64;
  const float* xb = x + (size_t)b * CC * NN;
  if (t < 192) { lw_s[t] = lnw[t]; lb_s[t] = lnb[t]; }
#pragma unroll
  for (int i = 0; i < 48; ++i) {
    int idx = i * 256 + t;
    int c = idx >> 6, n = idx & 63;
    xt[c * 65 + n] = xb[(size_t)c * NN + n0 + n];
  }
  __syncthreads();
  {
    int n = t & 63, part = t >> 6;
    float s = 0.f, s2 = 0.f;
#pragma unroll
    for (int c = part * 48; c < part * 48 + 48; ++c) {
      float v = xt[c * 65 + n];
      s += v; s2 += v * v;
    }
    psum[part][n] = s; psq[part][n] = s2;
  }
  __syncthreads();
  if (t < 64) {
    float s = psum[0][t] + psum[1][t] + psum[2][t] + psum[3][t];
    float s2 = psq[0][t] + psq[1][t] + psq[2][t] + psq[3][t];
    float mu = s * (1.0f / 192.0f);
    float var = s2 * (1.0f / 192.0f) - mu * mu;
    mu_s[t] = mu;
    rs_s[t] = rsqrtf(var + 1e-5f);
  }
  __syncthreads();
#pragma unroll
  for (int i = 0; i < 12; ++i) {
    int u = i * 256 + t;
    int n = u / 48, cq = (u % 48) * 4;
    float mu = mu_s[n], rs = rs_s[n];
    float v0 = (xt[(cq + 0) * 65 + n] - mu) * rs * lw_s[cq + 0] + lb_s[cq + 0];
    float v1 = (xt[(cq + 1) * 65 + n] - mu) * rs * lw_s[cq + 1] + lb_s[cq + 1];
    float v2 = (xt[(cq + 2) * 65 + n] - mu) * rs * lw_s[cq + 2] + lb_s[cq + 2];
    float v3 = (xt[(cq + 3) * 65 + n] - mu) * rs * lw_s[cq + 3] + lb_s[cq + 3];
    uint2 o;
    o.x = cvtpk(v0, v1);
    o.y = cvtpk(v2, v3);
    *(uint2*)&xn[((size_t)(b * NN + n0 + n)) * CC + cq] = o;
  }
}

// ---------------------------------------------------------------------------
// Kernel 1b: one-time W f32->bf16 conversion (was redone 576x per W tile)
// ---------------------------------------------------------------------------
__global__ __launch_bounds__(256) void wconv_kernel(
    const float* __restrict__ Wq, const float* __restrict__ Wk,
    const float* __restrict__ Wv, u16* __restrict__ wbf) {
  int z = blockIdx.y;
  const float* W = (z == 0) ? Wq : (z == 1 ? Wk : Wv);
  u16* o = wbf + (size_t)z * 36864;
  int idx = (blockIdx.x * 256 + (int)threadIdx.x) * 8;  // 18*256*8 = 36864
  float4 f0 = *(const float4*)&W[idx];
  float4 f1 = *(const float4*)&W[idx + 4];
  uint4 v;
  v.x = cvtpk(f0.x, f0.y);
  v.y = cvtpk(f0.z, f0.w);
  v.z = cvtpk(f1.x, f1.y);
  v.w = cvtpk(f1.z, f1.w);
  *(uint4*)&o[idx] = v;
}

// ---------------------------------------------------------------------------
// Kernel 2: QKV projections, z-loop inside block. X tile staged ONCE (gll16),
// W tiles staged from pre-converted bf16 (gll16, no VALU). Grid (576, 3).
// ---------------------------------------------------------------------------
__global__ __launch_bounds__(256, 3) void qkv_gemm(
    const u16* __restrict__ xn, const u16* __restrict__ wbf,
    u16* __restrict__ qb, u16* __restrict__ kb, u16* __restrict__ vtb) {
  __shared__ u16 xs[12288];
  __shared__ u16 wsm[12288];
  int t = threadIdx.x, w = t >> 6, lane = t & 63, l15 = lane & 15, qd = lane >> 4;
  int m0 = blockIdx.x * 64, n0 = blockIdx.y * 64;

  // stage X tile [64][192] swzK via gll (inverse-swizzled source)
#pragma unroll
  for (int i = 0; i < 6; ++i) {
    int cid = i * 4 + w, sc = cid * 64 + lane;
    int row = sc / 24, pc = sc % 24;
    int gc = (pc & ~7) | ((pc ^ row) & 7);
    gll16(xn + (size_t)(m0 + row) * 192 + gc * 8, xs + cid * 512);
  }
  // stage W(0)
#pragma unroll
  for (int i = 0; i < 6; ++i) {
    int cid = i * 4 + w, sc = cid * 64 + lane;
    int row = sc / 24, pc = sc % 24;
    int gc = (pc & ~7) | ((pc ^ row) & 7);
    gll16(wbf + (size_t)(n0 + row) * 192 + gc * 8, wsm + cid * 512);
  }

  bf16x8 a[6];
  const f32x4 fz = {0.f, 0.f, 0.f, 0.f};
  for (int z = 0; z < 3; ++z) {
    asm volatile("s_waitcnt vmcnt(0) lgkmcnt(0)\ns_barrier" ::: "memory");
    if (z == 0) {
#pragma unroll
      for (int kk = 0; kk < 6; ++kk)
        a[kk] = *(const bf16x8*)&xs[swzK(w * 16 + l15, kk * 32 + qd * 8)];
    }
    f32x4 acc[4];
#pragma unroll
    for (int ct = 0; ct < 4; ++ct) {
      acc[ct] = fz;
#pragma unroll
      for (int kk = 0; kk < 6; ++kk) {
        bf16x8 bfr = *(const bf16x8*)&wsm[swzK(ct * 16 + l15, kk * 32 + qd * 8)];
        acc[ct] = __builtin_amdgcn_mfma_f32_16x16x32_bf16(a[kk], bfr, acc[ct], 0, 0, 0);
      }
    }
    asm volatile("s_waitcnt lgkmcnt(0)\ns_barrier" ::: "memory");  // wsm reads done
    if (z < 2) {
      // stage W(z+1), flies under the C-write
#pragma unroll
      for (int i = 0; i < 6; ++i) {
        int cid = i * 4 + w, sc = cid * 64 + lane;
        int row = sc / 24, pc = sc % 24;
        int gc = (pc & ~7) | ((pc ^ row) & 7);
        gll16(wbf + (size_t)(z + 1) * 36864 + (size_t)(n0 + row) * 192 + gc * 8,
              wsm + cid * 512);
      }
      u16* outp = (z == 0) ? qb : kb;
#pragma unroll
      for (int ct = 0; ct < 4; ++ct)
#pragma unroll
        for (int r = 0; r < 4; ++r) {
          int m = m0 + w * 16 + qd * 4 + r;
          outp[(size_t)m * 192 + n0 + ct * 16 + l15] = bf16bits(acc[ct][r]);
        }
    } else {
      // V: transpose 64x64 C-tile via xs (X frags already in regs), store vt
#pragma unroll
      for (int ct = 0; ct < 4; ++ct)
#pragma unroll
        for (int r = 0; r < 4; ++r)
          xs[swz64(ct * 16 + l15, w * 16 + qd * 4 + r)] = bf16bits(acc[ct][r]);
      __syncthreads();
      int bb = blockIdx.x / 36, nb = (blockIdx.x % 36) * 64;
#pragma unroll
      for (int i = 0; i < 16; ++i) {
        int idx = i * 256 + t;
        int d = idx >> 6, nn = idx & 63;
        vtb[(size_t)bb * 192 * NN + (size_t)(n0 + d) * NN + nb + nn] = xs[swz64(d, nn)];
      }
    }
  }
}

// ---------------------------------------------------------------------------
// Kernel 3: single-pass fused attention v5 — 2 barriers/iter, V double-buffer.
// Each wave computes the FULL 64-k S (24 MFMA; duplicate across ch-pair) so
// both P-sets live entirely in registers (no pex exchange, no mid barrier).
// V(kt+1) issued at iter top -> full-iteration latency coverage; K(kt+1)
// issued at the lgkm barrier, covered by PV. LDS 72KB -> 2 blocks/CU.
// ---------------------------------------------------------------------------
__global__ __launch_bounds__(256, 2) void attn_fused(
    const u16* __restrict__ qb, const u16* __restrict__ kb,
    const u16* __restrict__ vtb, const float* __restrict__ w1p,
    const float* __restrict__ w2p, const float* __restrict__ x,
    float* __restrict__ out) {
  __shared__ u16 sm[36864];            // K@0 24KB | V0@12288 24KB | V1@24576 24KB
  float* olds = (float*)sm;            // epilogue overlay [192][64] f32 (48KB)
  float* lred = (float*)(sm + 24576);  // epilogue row-sum redistribution (V1 region)

  int t = threadIdx.x, w = t >> 6, lane = t & 63;
  int l31 = lane & 31, hi = lane >> 5;
  int qh = w >> 1, ch = w & 1;
  int bid = blockIdx.x;
  int xcd = bid & 7, j = bid >> 3;
  int b = xcd * 2 + (j >= 36 ? 1 : 0);
  int qt = (j >= 36) ? j - 36 : j;

  const u16* Kg = kb + (size_t)b * NN * CC;
  const u16* Vg = vtb + (size_t)b * CC * NN;
  const u16* Qr = qb + ((size_t)b * NN + qt * 64 + qh * 32 + l31) * CC + hi * 8;
  bf16x8 qf[12];
#pragma unroll
  for (int ks = 0; ks < 12; ++ks) qf[ks] = *(const bf16x8*)(Qr + ks * 16);

  float e1 = __expf(w1p[0]), e2 = __expf(w2p[0]);
  float den = e1 + e2;
  float c1f = e1 / den, c2f = e2 / den;

  f32x16 z16;
#pragma unroll
  for (int i = 0; i < 16; ++i) z16[i] = 0.f;
  f32x16 os[3], orl[3];
#pragma unroll
  for (int i = 0; i < 3; ++i) { os[i] = z16; orl[i] = z16; }
  float lsum = 0.f;

#define STAGE_K(KT)                                                        \
  {                                                                        \
    _Pragma("unroll") for (int i = 0; i < 6; ++i) {                        \
      int cid = i * 4 + w, sc = cid * 64 + lane;                           \
      int row = sc / 24, pc = sc % 24;                                     \
      int gc = (pc & ~7) | ((pc ^ row) & 7);                               \
      gll16(Kg + ((size_t)(KT) * 64 + row) * CC + gc * 8, sm + cid * 512); \
    }                                                                      \
  }
#define STAGE_V(KT, BUF)                                                   \
  {                                                                        \
    _Pragma("unroll") for (int i = 0; i < 6; ++i) {                        \
      int cid = i * 4 + w, sc = cid * 64 + lane;                           \
      int d = sc >> 3, pc = sc & 7, gc = (pc ^ d) & 7;                     \
      gll16(Vg + (size_t)d * NN + (KT) * 64 + gc * 8,                      \
            sm + 12288 + (BUF) * 12288 + cid * 512);                       \
    }                                                                      \
  }

  // prologue: K(0) + V(0)->buf0 in flight
  STAGE_K(0);
  STAGE_V(0, 0);

  alignas(16) uint32_t pS[4][4], pR[4][4];

  for (int kt = 0; kt < 36; ++kt) {
    // A: K(kt) (covered by PV(kt-1)) and V(kt) (covered ~1 full iter) landed;
    // all previous LDS reads drained.
    asm volatile("s_waitcnt vmcnt(0) lgkmcnt(0)\ns_barrier" ::: "memory");
    if (kt + 1 < 36) STAGE_V(kt + 1, (kt + 1) & 1);

    // ---- S(kt) full 64-k (both halves), blend, pack to 4+4 A-frags ----
#pragma unroll
    for (int kblk = 0; kblk < 2; ++kblk) {
      f32x16 sA0 = z16, sA1 = z16;
      __builtin_amdgcn_s_setprio(1);
#pragma unroll
      for (int ks = 0; ks < 6; ++ks) {
        bf16x8 k0 = *(const bf16x8*)&sm[swzK(kblk * 32 + l31, (2 * ks) * 16 + hi * 8)];
        bf16x8 k1 = *(const bf16x8*)&sm[swzK(kblk * 32 + l31, (2 * ks + 1) * 16 + hi * 8)];
        sA0 = __builtin_amdgcn_mfma_f32_32x32x16_bf16(k0, qf[2 * ks], sA0, 0, 0, 0);
        sA1 = __builtin_amdgcn_mfma_f32_32x32x16_bf16(k1, qf[2 * ks + 1], sA1, 0, 0, 0);
      }
      __builtin_amdgcn_s_setprio(0);
      uint32_t WS[8], WR[8];
#pragma unroll
      for (int g = 0; g < 4; ++g) {
        float sv0 = sA0[4 * g + 0] + sA1[4 * g + 0];
        float sv1 = sA0[4 * g + 1] + sA1[4 * g + 1];
        float sv2 = sA0[4 * g + 2] + sA1[4 * g + 2];
        float sv3 = sA0[4 * g + 3] + sA1[4 * g + 3];
        float ev0 = __expf(fminf(sv0, 60.f));
        float ev1 = __expf(fminf(sv1, 60.f));
        float ev2 = __expf(fminf(sv2, 60.f));
        float ev3 = __expf(fminf(sv3, 60.f));
        float r0 = fmaxf(sv0, 0.f), r1 = fmaxf(sv1, 0.f);
        float r2 = fmaxf(sv2, 0.f), r3 = fmaxf(sv3, 0.f);
        lsum += (ev0 + ev1) + (ev2 + ev3);
        WS[2 * g] = cvtpk(ev0, ev1);
        WS[2 * g + 1] = cvtpk(ev2, ev3);
        WR[2 * g] = cvtpk(r0 * r0, r1 * r1);
        WR[2 * g + 1] = cvtpk(r2 * r2, r3 * r3);
      }
      uint32_t XS[8], XR[8];
#pragma unroll
      for (int jj = 0; jj < 8; ++jj) {
        XS[jj] = __shfl_xor(WS[jj], 32);
        XR[jj] = __shfl_xor(WR[jj], 32);
      }
      pS[2 * kblk][0] = hi ? XS[2] : WS[0]; pS[2 * kblk][1] = hi ? XS[3] : WS[1];
      pS[2 * kblk][2] = hi ? WS[2] : XS[0]; pS[2 * kblk][3] = hi ? WS[3] : XS[1];
      pS[2 * kblk + 1][0] = hi ? XS[6] : WS[4]; pS[2 * kblk + 1][1] = hi ? XS[7] : WS[5];
      pS[2 * kblk + 1][2] = hi ? WS[6] : XS[4]; pS[2 * kblk + 1][3] = hi ? WS[7] : XS[5];
      pR[2 * kblk][0] = hi ? XR[2] : WR[0]; pR[2 * kblk][1] = hi ? XR[3] : WR[1];
      pR[2 * kblk][2] = hi ? WR[2] : XR[0]; pR[2 * kblk][3] = hi ? WR[3] : XR[1];
      pR[2 * kblk + 1][0] = hi ? XR[6] : WR[4]; pR[2 * kblk + 1][1] = hi ? XR[7] : WR[5];
      pR[2 * kblk + 1][2] = hi ? WR[6] : XR[4]; pR[2 * kblk + 1][3] = hi ? WR[7] : XR[5];
    }

    // B: all K reads done -> K region free for restage (lgkm only; V(kt+1)
    // glls stay in flight, counted-vmcnt style)
    asm volatile("s_waitcnt lgkmcnt(0)\ns_barrier" ::: "memory");
    if (kt + 1 < 36) STAGE_K(kt + 1);  // flies under PV(kt)

    // ---- PV(kt): dual accumulators, V-frag shared between sets ----
    const u16* vl = sm + 12288 + (kt & 1) * 12288;
    __builtin_amdgcn_s_setprio(1);
#pragma unroll
    for (int dt = 0; dt < 3; ++dt) {
      int d = ch * 96 + dt * 32 + l31;
#pragma unroll
      for (int ks = 0; ks < 4; ++ks) {
        bf16x8 vf = *(const bf16x8*)&vl[swz64(d, ks * 16 + hi * 8)];
        os[dt] = __builtin_amdgcn_mfma_f32_32x32x16_bf16(
            *(const bf16x8*)pS[ks], vf, os[dt], 0, 0, 0);
        orl[dt] = __builtin_amdgcn_mfma_f32_32x32x16_bf16(
            *(const bf16x8*)pR[ks], vf, orl[dt], 0, 0, 0);
      }
    }
    __builtin_amdgcn_s_setprio(0);
  }

  // ---- epilogue: lsum redistribute (lane q -> reg q), blend, store ----
  lsum += __shfl_xor(lsum, 32);   // fold hi halves -> full row sum for q=l31
  __syncthreads();                // PV(35) LDS reads done (V1 region free)
  if (ch == 0 && hi == 0) lred[qh * 32 + l31] = lsum;
  __syncthreads();
  float linv[16];
#pragma unroll
  for (int r = 0; r < 16; ++r) {
    int m = (r & 3) + 8 * (r >> 2) + 4 * hi;
    linv[r] = c1f / lred[qh * 32 + m];
  }
#pragma unroll
  for (int dt = 0; dt < 3; ++dt) {
    int d = ch * 96 + dt * 32 + l31;
#pragma unroll
    for (int r = 0; r < 16; ++r) {
      int m = (r & 3) + 8 * (r >> 2) + 4 * hi;
      int q = qh * 32 + m;
      olds[d * 64 + ((q & ~31) | ((q ^ d) & 31))] =
          os[dt][r] * linv[r] + c2f * orl[dt][r];
    }
  }
  __syncthreads();
  const float* xb = x + (size_t)b * CC * NN + qt * 64;
  float* ob = out + (size_t)b * CC * NN + qt * 64;
#pragma unroll
  for (int i = 0; i < 48; ++i) {
    int idx = i * 256 + t;
    int c = idx >> 6, nn = idx & 63;
    float v = olds[c * 64 + ((nn & ~31) | ((nn ^ c) & 31))];
    ob[(size_t)c * NN + nn] = v + xb[(size_t)c * NN + nn];
  }
#undef STAGE_K
#undef STAGE_V
}

// ---------------------------------------------------------------------------
extern "C" void kernel_launch(void* const* d_in, const int* in_sizes, int n_in,
                              void* d_out, int out_size, void* d_ws, size_t ws_size,
                              hipStream_t stream) {
  (void)in_sizes; (void)n_in; (void)out_size; (void)ws_size;
  const float* x   = (const float*)d_in[0];
  const float* lnw = (const float*)d_in[1];
  const float* lnb = (const float*)d_in[2];
  const float* Wq  = (const float*)d_in[3];
  const float* Wk  = (const float*)d_in[4];
  const float* Wv  = (const float*)d_in[5];
  const float* w1  = (const float*)d_in[6];
  const float* w2  = (const float*)d_in[7];
  float* out = (float*)d_out;

  u16* xn = (u16*)d_ws;
  size_t per = (size_t)NBATCH * NN * CC;
  u16* qb  = xn + per;
  u16* kb  = qb + per;
  u16* vtb = kb + per;
  u16* wbf = vtb + per;   // 3*192*192 bf16 = 221 KB

  ln_kernel<<<dim3(36, 16), 256, 0, stream>>>(x, lnw, lnb, xn);
  wconv_kernel<<<dim3(18, 3), 256, 0, stream>>>(Wq, Wk, Wv, wbf);
  qkv_gemm<<<dim3(576, 3), 256, 0, stream>>>(xn, wbf, qb, kb, vtb);
  attn_fused<<<dim3(576), 256, 0, stream>>>(qb, kb, vtb, w1, w2, x, out);
}

// Round 10
// 603.840 us; speedup vs baseline: 1.0080x; 1.0080x over previous
//
#include <hip/hip_runtime.h>

#define NN 2304
#define CC 192
#define NBATCH 16

typedef unsigned short u16;
typedef __bf16 bf16x8 __attribute__((ext_vector_type(8)));
typedef float f32x4 __attribute__((ext_vector_type(4)));
typedef float f32x16 __attribute__((ext_vector_type(16)));

__device__ __forceinline__ u16 bf16bits(float f) {
  union { float f; unsigned u; } v;
  v.f = f;
  unsigned r = v.u + 0x7FFFu + ((v.u >> 16) & 1u);
  return (u16)(r >> 16);
}

// pack two f32 -> u32 of 2 bf16 (RNE), single HW instr
__device__ __forceinline__ uint32_t cvtpk(float lo, float hi) {
  uint32_t d;
  asm("v_cvt_pk_bf16_f32 %0, %1, %2" : "=v"(d) : "v"(lo), "v"(hi));
  return d;
}

// XOR-swizzled LDS element index for a [rows][192] bf16 tile (row stride 192).
__device__ __forceinline__ int swzK(int row, int col) {
  int ch = col >> 3;
  int phys = (ch & ~7) | ((ch ^ row) & 7);
  return row * 192 + (phys << 3) + (col & 7);
}
// Same for [rows][64] bf16 tiles (8 chunks per row).
__device__ __forceinline__ int swz64(int row, int col) {
  int ch = (col >> 3) ^ row;
  return (row << 6) | ((ch & 7) << 3) | (col & 7);
}

// direct global->LDS 16B DMA; dest = wave-uniform base + lane*16
__device__ __forceinline__ void gll16(const u16* g, u16* l) {
  __builtin_amdgcn_global_load_lds(
      (const __attribute__((address_space(1))) u16*)g,
      (__attribute__((address_space(3))) u16*)l, 16, 0, 0);
}

// ---------------------------------------------------------------------------
// Kernel 1: LayerNorm over C, x[b,c,n] (fp32) -> xn[(b*N+n), c] (bf16)
// ---------------------------------------------------------------------------
__global__ __launch_bounds__(256) void ln_kernel(
    const float* __restrict__ x, const float* __restrict__ lnw,
    const float* __restrict__ lnb, u16* __restrict__ xn) {
  __shared__ float xt[192 * 65];
  __shared__ float psum[4][64], psq[4][64];
  __shared__ float mu_s[64], rs_s[64];
  __shared__ float lw_s[192], lb_s[192];
  int t = threadIdx.x;
  int b = blockIdx.y, n0 = blockIdx.x * 64;
  const float* xb = x + (size_t)b * CC * NN;
  if (t < 192) { lw_s[t] = lnw[t]; lb_s[t] = lnb[t]; }
#pragma unroll
  for (int i = 0; i < 48; ++i) {
    int idx = i * 256 + t;
    int c = idx >> 6, n = idx & 63;
    xt[c * 65 + n] = xb[(size_t)c * NN + n0 + n];
  }
  __syncthreads();
  {
    int n = t & 63, part = t >> 6;
    float s = 0.f, s2 = 0.f;
#pragma unroll
    for (int c = part * 48; c < part * 48 + 48; ++c) {
      float v = xt[c * 65 + n];
      s += v; s2 += v * v;
    }
    psum[part][n] = s; psq[part][n] = s2;
  }
  __syncthreads();
  if (t < 64) {
    float s = psum[0][t] + psum[1][t] + psum[2][t] + psum[3][t];
    float s2 = psq[0][t] + psq[1][t] + psq[2][t] + psq[3][t];
    float mu = s * (1.0f / 192.0f);
    float var = s2 * (1.0f / 192.0f) - mu * mu;
    mu_s[t] = mu;
    rs_s[t] = rsqrtf(var + 1e-5f);
  }
  __syncthreads();
#pragma unroll
  for (int i = 0; i < 12; ++i) {
    int u = i * 256 + t;
    int n = u / 48, cq = (u % 48) * 4;
    float mu = mu_s[n], rs = rs_s[n];
    float v0 = (xt[(cq + 0) * 65 + n] - mu) * rs * lw_s[cq + 0] + lb_s[cq + 0];
    float v1 = (xt[(cq + 1) * 65 + n] - mu) * rs * lw_s[cq + 1] + lb_s[cq + 1];
    float v2 = (xt[(cq + 2) * 65 + n] - mu) * rs * lw_s[cq + 2] + lb_s[cq + 2];
    float v3 = (xt[(cq + 3) * 65 + n] - mu) * rs * lw_s[cq + 3] + lb_s[cq + 3];
    uint2 o;
    o.x = cvtpk(v0, v1);
    o.y = cvtpk(v2, v3);
    *(uint2*)&xn[((size_t)(b * NN + n0 + n)) * CC + cq] = o;
  }
}

// ---------------------------------------------------------------------------
// Kernel 1b: one-time W f32->bf16 conversion
// ---------------------------------------------------------------------------
__global__ __launch_bounds__(256) void wconv_kernel(
    const float* __restrict__ Wq, const float* __restrict__ Wk,
    const float* __restrict__ Wv, u16* __restrict__ wbf) {
  int z = blockIdx.y;
  const float* W = (z == 0) ? Wq : (z == 1 ? Wk : Wv);
  u16* o = wbf + (size_t)z * 36864;
  int idx = (blockIdx.x * 256 + (int)threadIdx.x) * 8;
  float4 f0 = *(const float4*)&W[idx];
  float4 f1 = *(const float4*)&W[idx + 4];
  uint4 v;
  v.x = cvtpk(f0.x, f0.y);
  v.y = cvtpk(f0.z, f0.w);
  v.z = cvtpk(f1.x, f1.y);
  v.w = cvtpk(f1.z, f1.w);
  *(uint4*)&o[idx] = v;
}

// ---------------------------------------------------------------------------
// Kernel 2: QKV projections, z-loop inside block. X staged once via gll.
// ---------------------------------------------------------------------------
__global__ __launch_bounds__(256, 3) void qkv_gemm(
    const u16* __restrict__ xn, const u16* __restrict__ wbf,
    u16* __restrict__ qb, u16* __restrict__ kb, u16* __restrict__ vtb) {
  __shared__ u16 xs[12288];
  __shared__ u16 wsm[12288];
  int t = threadIdx.x, w = t >> 6, lane = t & 63, l15 = lane & 15, qd = lane >> 4;
  int m0 = blockIdx.x * 64, n0 = blockIdx.y * 64;

#pragma unroll
  for (int i = 0; i < 6; ++i) {
    int cid = i * 4 + w, sc = cid * 64 + lane;
    int row = sc / 24, pc = sc % 24;
    int gc = (pc & ~7) | ((pc ^ row) & 7);
    gll16(xn + (size_t)(m0 + row) * 192 + gc * 8, xs + cid * 512);
  }
#pragma unroll
  for (int i = 0; i < 6; ++i) {
    int cid = i * 4 + w, sc = cid * 64 + lane;
    int row = sc / 24, pc = sc % 24;
    int gc = (pc & ~7) | ((pc ^ row) & 7);
    gll16(wbf + (size_t)(n0 + row) * 192 + gc * 8, wsm + cid * 512);
  }

  bf16x8 a[6];
  const f32x4 fz = {0.f, 0.f, 0.f, 0.f};
  for (int z = 0; z < 3; ++z) {
    asm volatile("s_waitcnt vmcnt(0) lgkmcnt(0)\ns_barrier" ::: "memory");
    if (z == 0) {
#pragma unroll
      for (int kk = 0; kk < 6; ++kk)
        a[kk] = *(const bf16x8*)&xs[swzK(w * 16 + l15, kk * 32 + qd * 8)];
    }
    f32x4 acc[4];
#pragma unroll
    for (int ct = 0; ct < 4; ++ct) {
      acc[ct] = fz;
#pragma unroll
      for (int kk = 0; kk < 6; ++kk) {
        bf16x8 bfr = *(const bf16x8*)&wsm[swzK(ct * 16 + l15, kk * 32 + qd * 8)];
        acc[ct] = __builtin_amdgcn_mfma_f32_16x16x32_bf16(a[kk], bfr, acc[ct], 0, 0, 0);
      }
    }
    asm volatile("s_waitcnt lgkmcnt(0)\ns_barrier" ::: "memory");
    if (z < 2) {
#pragma unroll
      for (int i = 0; i < 6; ++i) {
        int cid = i * 4 + w, sc = cid * 64 + lane;
        int row = sc / 24, pc = sc % 24;
        int gc = (pc & ~7) | ((pc ^ row) & 7);
        gll16(wbf + (size_t)(z + 1) * 36864 + (size_t)(n0 + row) * 192 + gc * 8,
              wsm + cid * 512);
      }
      u16* outp = (z == 0) ? qb : kb;
#pragma unroll
      for (int ct = 0; ct < 4; ++ct)
#pragma unroll
        for (int r = 0; r < 4; ++r) {
          int m = m0 + w * 16 + qd * 4 + r;
          outp[(size_t)m * 192 + n0 + ct * 16 + l15] = bf16bits(acc[ct][r]);
        }
    } else {
#pragma unroll
      for (int ct = 0; ct < 4; ++ct)
#pragma unroll
        for (int r = 0; r < 4; ++r)
          xs[swz64(ct * 16 + l15, w * 16 + qd * 4 + r)] = bf16bits(acc[ct][r]);
      __syncthreads();
      int bb = blockIdx.x / 36, nb = (blockIdx.x % 36) * 64;
#pragma unroll
      for (int i = 0; i < 16; ++i) {
        int idx = i * 256 + t;
        int d = idx >> 6, nn = idx & 63;
        vtb[(size_t)bb * 192 * NN + (size_t)(n0 + d) * NN + nb + nn] = xs[swz64(d, nn)];
      }
    }
  }
}

// ---------------------------------------------------------------------------
// Kernel 3: single-pass fused attention v6 — R9's 2-barrier/V-dbuf structure
// with the spill fixed: Q frags are NOT kernel-resident. They are reloaded
// from global each iteration (L1-hot: block's own 24KB Q tile), with an
// opaque-zero asm dependency to stop the compiler hoisting the loads out of
// the loop. Peak live regs ~230 < 256 cap -> no scratch.
// ---------------------------------------------------------------------------
__global__ __launch_bounds__(256, 2) void attn_fused(
    const u16* __restrict__ qb, const u16* __restrict__ kb,
    const u16* __restrict__ vtb, const float* __restrict__ w1p,
    const float* __restrict__ w2p, const float* __restrict__ x,
    float* __restrict__ out) {
  __shared__ u16 sm[36864];            // K@0 24KB | V0@12288 24KB | V1@24576 24KB
  float* olds = (float*)sm;            // epilogue overlay [192][64] f32 (48KB)
  float* lred = (float*)(sm + 24576);  // epilogue row-sum redistribution

  int t = threadIdx.x, w = t >> 6, lane = t & 63;
  int l31 = lane & 31, hi = lane >> 5;
  int qh = w >> 1, ch = w & 1;
  int bid = blockIdx.x;
  int xcd = bid & 7, j = bid >> 3;
  int b = xcd * 2 + (j >= 36 ? 1 : 0);
  int qt = (j >= 36) ? j - 36 : j;

  const u16* Kg = kb + (size_t)b * NN * CC;
  const u16* Vg = vtb + (size_t)b * CC * NN;
  const u16* Qr = qb + ((size_t)b * NN + qt * 64 + qh * 32 + l31) * CC + hi * 8;

  float e1 = __expf(w1p[0]), e2 = __expf(w2p[0]);
  float den = e1 + e2;
  float c1f = e1 / den, c2f = e2 / den;

  f32x16 z16;
#pragma unroll
  for (int i = 0; i < 16; ++i) z16[i] = 0.f;
  f32x16 os[3], orl[3];
#pragma unroll
  for (int i = 0; i < 3; ++i) { os[i] = z16; orl[i] = z16; }
  float lsum = 0.f;

#define STAGE_K(KT)                                                        \
  {                                                                        \
    _Pragma("unroll") for (int i = 0; i < 6; ++i) {                        \
      int cid = i * 4 + w, sc = cid * 64 + lane;                           \
      int row = sc / 24, pc = sc % 24;                                     \
      int gc = (pc & ~7) | ((pc ^ row) & 7);                               \
      gll16(Kg + ((size_t)(KT) * 64 + row) * CC + gc * 8, sm + cid * 512); \
    }                                                                      \
  }
#define STAGE_V(KT, BUF)                                                   \
  {                                                                        \
    _Pragma("unroll") for (int i = 0; i < 6; ++i) {                        \
      int cid = i * 4 + w, sc = cid * 64 + lane;                           \
      int d = sc >> 3, pc = sc & 7, gc = (pc ^ d) & 7;                     \
      gll16(Vg + (size_t)d * NN + (KT) * 64 + gc * 8,                      \
            sm + 12288 + (BUF) * 12288 + cid * 512);                       \
    }                                                                      \
  }

  // prologue: K(0) + V(0)->buf0 in flight
  STAGE_K(0);
  STAGE_V(0, 0);

  alignas(16) uint32_t pS[4][4], pR[4][4];

  for (int kt = 0; kt < 36; ++kt) {
    // A: K(kt) (covered by PV(kt-1)) and V(kt) (covered a full iter) landed.
    asm volatile("s_waitcnt vmcnt(0) lgkmcnt(0)\ns_barrier" ::: "memory");
    if (kt + 1 < 36) STAGE_V(kt + 1, (kt + 1) & 1);

    // Q frags: reloaded every iteration (L1-hot). Opaque zero defeats
    // loop-invariant hoisting so the 48 regs are NOT live across iters.
    int zq = 0;
    asm volatile("" : "+v"(zq));
    bf16x8 qf[12];
#pragma unroll
    for (int ks = 0; ks < 12; ++ks)
      qf[ks] = *(const bf16x8*)(Qr + zq + ks * 16);

    // ---- S(kt) full 64-k (both halves), blend, pack to 4+4 A-frags ----
#pragma unroll
    for (int kblk = 0; kblk < 2; ++kblk) {
      f32x16 sA0 = z16, sA1 = z16;
      __builtin_amdgcn_s_setprio(1);
#pragma unroll
      for (int ks = 0; ks < 6; ++ks) {
        bf16x8 k0 = *(const bf16x8*)&sm[swzK(kblk * 32 + l31, (2 * ks) * 16 + hi * 8)];
        bf16x8 k1 = *(const bf16x8*)&sm[swzK(kblk * 32 + l31, (2 * ks + 1) * 16 + hi * 8)];
        sA0 = __builtin_amdgcn_mfma_f32_32x32x16_bf16(k0, qf[2 * ks], sA0, 0, 0, 0);
        sA1 = __builtin_amdgcn_mfma_f32_32x32x16_bf16(k1, qf[2 * ks + 1], sA1, 0, 0, 0);
      }
      __builtin_amdgcn_s_setprio(0);
      uint32_t WS[8], WR[8];
#pragma unroll
      for (int g = 0; g < 4; ++g) {
        float sv0 = sA0[4 * g + 0] + sA1[4 * g + 0];
        float sv1 = sA0[4 * g + 1] + sA1[4 * g + 1];
        float sv2 = sA0[4 * g + 2] + sA1[4 * g + 2];
        float sv3 = sA0[4 * g + 3] + sA1[4 * g + 3];
        float ev0 = __expf(fminf(sv0, 60.f));
        float ev1 = __expf(fminf(sv1, 60.f));
        float ev2 = __expf(fminf(sv2, 60.f));
        float ev3 = __expf(fminf(sv3, 60.f));
        float r0 = fmaxf(sv0, 0.f), r1 = fmaxf(sv1, 0.f);
        float r2 = fmaxf(sv2, 0.f), r3 = fmaxf(sv3, 0.f);
        lsum += (ev0 + ev1) + (ev2 + ev3);
        WS[2 * g] = cvtpk(ev0, ev1);
        WS[2 * g + 1] = cvtpk(ev2, ev3);
        WR[2 * g] = cvtpk(r0 * r0, r1 * r1);
        WR[2 * g + 1] = cvtpk(r2 * r2, r3 * r3);
      }
      uint32_t XS[8], XR[8];
#pragma unroll
      for (int jj = 0; jj < 8; ++jj) {
        XS[jj] = __shfl_xor(WS[jj], 32);
        XR[jj] = __shfl_xor(WR[jj], 32);
      }
      pS[2 * kblk][0] = hi ? XS[2] : WS[0]; pS[2 * kblk][1] = hi ? XS[3] : WS[1];
      pS[2 * kblk][2] = hi ? WS[2] : XS[0]; pS[2 * kblk][3] = hi ? WS[3] : XS[1];
      pS[2 * kblk + 1][0] = hi ? XS[6] : WS[4]; pS[2 * kblk + 1][1] = hi ? XS[7] : WS[5];
      pS[2 * kblk + 1][2] = hi ? WS[6] : XS[4]; pS[2 * kblk + 1][3] = hi ? WS[7] : XS[5];
      pR[2 * kblk][0] = hi ? XR[2] : WR[0]; pR[2 * kblk][1] = hi ? XR[3] : WR[1];
      pR[2 * kblk][2] = hi ? WR[2] : XR[0]; pR[2 * kblk][3] = hi ? WR[3] : XR[1];
      pR[2 * kblk + 1][0] = hi ? XR[6] : WR[4]; pR[2 * kblk + 1][1] = hi ? XR[7] : WR[5];
      pR[2 * kblk + 1][2] = hi ? WR[6] : XR[4]; pR[2 * kblk + 1][3] = hi ? WR[7] : XR[5];
    }

    // B: all K reads done -> K region free (lgkm only; V(kt+1) stays in flight)
    asm volatile("s_waitcnt lgkmcnt(0)\ns_barrier" ::: "memory");
    if (kt + 1 < 36) STAGE_K(kt + 1);  // flies under PV(kt)

    // ---- PV(kt): dual accumulators, V-frag shared between sets ----
    const u16* vl = sm + 12288 + (kt & 1) * 12288;
    __builtin_amdgcn_s_setprio(1);
#pragma unroll
    for (int dt = 0; dt < 3; ++dt) {
      int d = ch * 96 + dt * 32 + l31;
#pragma unroll
      for (int ks = 0; ks < 4; ++ks) {
        bf16x8 vf = *(const bf16x8*)&vl[swz64(d, ks * 16 + hi * 8)];
        os[dt] = __builtin_amdgcn_mfma_f32_32x32x16_bf16(
            *(const bf16x8*)pS[ks], vf, os[dt], 0, 0, 0);
        orl[dt] = __builtin_amdgcn_mfma_f32_32x32x16_bf16(
            *(const bf16x8*)pR[ks], vf, orl[dt], 0, 0, 0);
      }
    }
    __builtin_amdgcn_s_setprio(0);
  }

  // ---- epilogue: lsum redistribute (lane q -> reg q), blend, store ----
  lsum += __shfl_xor(lsum, 32);   // fold hi halves -> full row sum for q=l31
  __syncthreads();                // PV(35) LDS reads done
  if (ch == 0 && hi == 0) lred[qh * 32 + l31] = lsum;
  __syncthreads();
  float linv[16];
#pragma unroll
  for (int r = 0; r < 16; ++r) {
    int m = (r & 3) + 8 * (r >> 2) + 4 * hi;
    linv[r] = c1f / lred[qh * 32 + m];
  }
#pragma unroll
  for (int dt = 0; dt < 3; ++dt) {
    int d = ch * 96 + dt * 32 + l31;
#pragma unroll
    for (int r = 0; r < 16; ++r) {
      int m = (r & 3) + 8 * (r >> 2) + 4 * hi;
      int q = qh * 32 + m;
      olds[d * 64 + ((q & ~31) | ((q ^ d) & 31))] =
          os[dt][r] * linv[r] + c2f * orl[dt][r];
    }
  }
  __syncthreads();
  const float* xb = x + (size_t)b * CC * NN + qt * 64;
  float* ob = out + (size_t)b * CC * NN + qt * 64;
#pragma unroll
  for (int i = 0; i < 48; ++i) {
    int idx = i * 256 + t;
    int c = idx >> 6, nn = idx & 63;
    float v = olds[c * 64 + ((nn & ~31) | ((nn ^ c) & 31))];
    ob[(size_t)c * NN + nn] = v + xb[(size_t)c * NN + nn];
  }
#undef STAGE_K
#undef STAGE_V
}

// ---------------------------------------------------------------------------
extern "C" void kernel_launch(void* const* d_in, const int* in_sizes, int n_in,
                              void* d_out, int out_size, void* d_ws, size_t ws_size,
                              hipStream_t stream) {
  (void)in_sizes; (void)n_in; (void)out_size; (void)ws_size;
  const float* x   = (const float*)d_in[0];
  const float* lnw = (const float*)d_in[1];
  const float* lnb = (const float*)d_in[2];
  const float* Wq  = (const float*)d_in[3];
  const float* Wk  = (const float*)d_in[4];
  const float* Wv  = (const float*)d_in[5];
  const float* w1  = (const float*)d_in[6];
  const float* w2  = (const float*)d_in[7];
  float* out = (float*)d_out;

  u16* xn = (u16*)d_ws;
  size_t per = (size_t)NBATCH * NN * CC;
  u16* qb  = xn + per;
  u16* kb  = qb + per;
  u16* vtb = kb + per;
  u16* wbf = vtb + per;   // 3*192*192 bf16 = 221 KB

  ln_kernel<<<dim3(36, 16), 256, 0, stream>>>(x, lnw, lnb, xn);
  wconv_kernel<<<dim3(18, 3), 256, 0, stream>>>(Wq, Wk, Wv, wbf);
  qkv_gemm<<<dim3(576, 3), 256, 0, stream>>>(xn, wbf, qb, kb, vtb);
  attn_fused<<<dim3(576), 256, 0, stream>>>(qb, kb, vtb, w1, w2, x, out);
}

// Round 11
// 285.881 us; speedup vs baseline: 2.1292x; 2.1122x over previous
//
#include <hip/hip_runtime.h>

#define NN 2304
#define CC 192
#define NBATCH 16

typedef unsigned short u16;
typedef __bf16 bf16x8 __attribute__((ext_vector_type(8)));
typedef float f32x4 __attribute__((ext_vector_type(4)));
typedef float f32x16 __attribute__((ext_vector_type(16)));

__device__ __forceinline__ u16 bf16bits(float f) {
  union { float f; unsigned u; } v;
  v.f = f;
  unsigned r = v.u + 0x7FFFu + ((v.u >> 16) & 1u);
  return (u16)(r >> 16);
}

// pack two f32 -> u32 of 2 bf16 (RNE), single HW instr
__device__ __forceinline__ uint32_t cvtpk(float lo, float hi) {
  uint32_t d;
  asm("v_cvt_pk_bf16_f32 %0, %1, %2" : "=v"(d) : "v"(lo), "v"(hi));
  return d;
}

// XOR-swizzled LDS element index for a [rows][192] bf16 tile (row stride 192).
__device__ __forceinline__ int swzK(int row, int col) {
  int ch = col >> 3;
  int phys = (ch & ~7) | ((ch ^ row) & 7);
  return row * 192 + (phys << 3) + (col & 7);
}
// Same for [rows][64] bf16 tiles (8 chunks per row).
__device__ __forceinline__ int swz64(int row, int col) {
  int ch = (col >> 3) ^ row;
  return (row << 6) | ((ch & 7) << 3) | (col & 7);
}

// direct global->LDS 16B DMA; dest = wave-uniform base + lane*16
__device__ __forceinline__ void gll16(const u16* g, u16* l) {
  __builtin_amdgcn_global_load_lds(
      (const __attribute__((address_space(1))) u16*)g,
      (__attribute__((address_space(3))) u16*)l, 16, 0, 0);
}

// ---------------------------------------------------------------------------
// Kernel 1: LayerNorm over C, x[b,c,n] (fp32) -> xn[(b*N+n), c] (bf16)
// ---------------------------------------------------------------------------
__global__ __launch_bounds__(256) void ln_kernel(
    const float* __restrict__ x, const float* __restrict__ lnw,
    const float* __restrict__ lnb, u16* __restrict__ xn) {
  __shared__ float xt[192 * 65];
  __shared__ float psum[4][64], psq[4][64];
  __shared__ float mu_s[64], rs_s[64];
  __shared__ float lw_s[192], lb_s[192];
  int t = threadIdx.x;
  int b = blockIdx.y, n0 = blockIdx.x * 64;
  const float* xb = x + (size_t)b * CC * NN;
  if (t < 192) { lw_s[t] = lnw[t]; lb_s[t] = lnb[t]; }
#pragma unroll
  for (int i = 0; i < 48; ++i) {
    int idx = i * 256 + t;
    int c = idx >> 6, n = idx & 63;
    xt[c * 65 + n] = xb[(size_t)c * NN + n0 + n];
  }
  __syncthreads();
  {
    int n = t & 63, part = t >> 6;
    float s = 0.f, s2 = 0.f;
#pragma unroll
    for (int c = part * 48; c < part * 48 + 48; ++c) {
      float v = xt[c * 65 + n];
      s += v; s2 += v * v;
    }
    psum[part][n] = s; psq[part][n] = s2;
  }
  __syncthreads();
  if (t < 64) {
    float s = psum[0][t] + psum[1][t] + psum[2][t] + psum[3][t];
    float s2 = psq[0][t] + psq[1][t] + psq[2][t] + psq[3][t];
    float mu = s * (1.0f / 192.0f);
    float var = s2 * (1.0f / 192.0f) - mu * mu;
    mu_s[t] = mu;
    rs_s[t] = rsqrtf(var + 1e-5f);
  }
  __syncthreads();
#pragma unroll
  for (int i = 0; i < 12; ++i) {
    int u = i * 256 + t;
    int n = u / 48, cq = (u % 48) * 4;
    float mu = mu_s[n], rs = rs_s[n];
    float v0 = (xt[(cq + 0) * 65 + n] - mu) * rs * lw_s[cq + 0] + lb_s[cq + 0];
    float v1 = (xt[(cq + 1) * 65 + n] - mu) * rs * lw_s[cq + 1] + lb_s[cq + 1];
    float v2 = (xt[(cq + 2) * 65 + n] - mu) * rs * lw_s[cq + 2] + lb_s[cq + 2];
    float v3 = (xt[(cq + 3) * 65 + n] - mu) * rs * lw_s[cq + 3] + lb_s[cq + 3];
    uint2 o;
    o.x = cvtpk(v0, v1);
    o.y = cvtpk(v2, v3);
    *(uint2*)&xn[((size_t)(b * NN + n0 + n)) * CC + cq] = o;
  }
}

// ---------------------------------------------------------------------------
// Kernel 1b: one-time W f32->bf16 conversion
// ---------------------------------------------------------------------------
__global__ __launch_bounds__(256) void wconv_kernel(
    const float* __restrict__ Wq, const float* __restrict__ Wk,
    const float* __restrict__ Wv, u16* __restrict__ wbf) {
  int z = blockIdx.y;
  const float* W = (z == 0) ? Wq : (z == 1 ? Wk : Wv);
  u16* o = wbf + (size_t)z * 36864;
  int idx = (blockIdx.x * 256 + (int)threadIdx.x) * 8;
  float4 f0 = *(const float4*)&W[idx];
  float4 f1 = *(const float4*)&W[idx + 4];
  uint4 v;
  v.x = cvtpk(f0.x, f0.y);
  v.y = cvtpk(f0.z, f0.w);
  v.z = cvtpk(f1.x, f1.y);
  v.w = cvtpk(f1.z, f1.w);
  *(uint4*)&o[idx] = v;
}

// ---------------------------------------------------------------------------
// Kernel 2: QKV projections, z-loop inside block. X staged once via gll.
// ---------------------------------------------------------------------------
__global__ __launch_bounds__(256, 3) void qkv_gemm(
    const u16* __restrict__ xn, const u16* __restrict__ wbf,
    u16* __restrict__ qb, u16* __restrict__ kb, u16* __restrict__ vtb) {
  __shared__ u16 xs[12288];
  __shared__ u16 wsm[12288];
  int t = threadIdx.x, w = t >> 6, lane = t & 63, l15 = lane & 15, qd = lane >> 4;
  int m0 = blockIdx.x * 64, n0 = blockIdx.y * 64;

#pragma unroll
  for (int i = 0; i < 6; ++i) {
    int cid = i * 4 + w, sc = cid * 64 + lane;
    int row = sc / 24, pc = sc % 24;
    int gc = (pc & ~7) | ((pc ^ row) & 7);
    gll16(xn + (size_t)(m0 + row) * 192 + gc * 8, xs + cid * 512);
  }
#pragma unroll
  for (int i = 0; i < 6; ++i) {
    int cid = i * 4 + w, sc = cid * 64 + lane;
    int row = sc / 24, pc = sc % 24;
    int gc = (pc & ~7) | ((pc ^ row) & 7);
    gll16(wbf + (size_t)(n0 + row) * 192 + gc * 8, wsm + cid * 512);
  }

  bf16x8 a[6];
  const f32x4 fz = {0.f, 0.f, 0.f, 0.f};
  for (int z = 0; z < 3; ++z) {
    asm volatile("s_waitcnt vmcnt(0) lgkmcnt(0)\ns_barrier" ::: "memory");
    if (z == 0) {
#pragma unroll
      for (int kk = 0; kk < 6; ++kk)
        a[kk] = *(const bf16x8*)&xs[swzK(w * 16 + l15, kk * 32 + qd * 8)];
    }
    f32x4 acc[4];
#pragma unroll
    for (int ct = 0; ct < 4; ++ct) {
      acc[ct] = fz;
#pragma unroll
      for (int kk = 0; kk < 6; ++kk) {
        bf16x8 bfr = *(const bf16x8*)&wsm[swzK(ct * 16 + l15, kk * 32 + qd * 8)];
        acc[ct] = __builtin_amdgcn_mfma_f32_16x16x32_bf16(a[kk], bfr, acc[ct], 0, 0, 0);
      }
    }
    asm volatile("s_waitcnt lgkmcnt(0)\ns_barrier" ::: "memory");
    if (z < 2) {
#pragma unroll
      for (int i = 0; i < 6; ++i) {
        int cid = i * 4 + w, sc = cid * 64 + lane;
        int row = sc / 24, pc = sc % 24;
        int gc = (pc & ~7) | ((pc ^ row) & 7);
        gll16(wbf + (size_t)(z + 1) * 36864 + (size_t)(n0 + row) * 192 + gc * 8,
              wsm + cid * 512);
      }
      u16* outp = (z == 0) ? qb : kb;
#pragma unroll
      for (int ct = 0; ct < 4; ++ct)
#pragma unroll
        for (int r = 0; r < 4; ++r) {
          int m = m0 + w * 16 + qd * 4 + r;
          outp[(size_t)m * 192 + n0 + ct * 16 + l15] = bf16bits(acc[ct][r]);
        }
    } else {
#pragma unroll
      for (int ct = 0; ct < 4; ++ct)
#pragma unroll
        for (int r = 0; r < 4; ++r)
          xs[swz64(ct * 16 + l15, w * 16 + qd * 4 + r)] = bf16bits(acc[ct][r]);
      __syncthreads();
      int bb = blockIdx.x / 36, nb = (blockIdx.x % 36) * 64;
#pragma unroll
      for (int i = 0; i < 16; ++i) {
        int idx = i * 256 + t;
        int d = idx >> 6, nn = idx & 63;
        vtb[(size_t)bb * 192 * NN + (size_t)(n0 + d) * NN + nb + nn] = xs[swz64(d, nn)];
      }
    }
  }
}

// ---------------------------------------------------------------------------
// Kernel 3: single-pass fused attention — REVERT to the R8-proven structure
// (190 µs, no spill): 3 barriers/iter, k-split S (12 MFMA/wave), dual P-sets
// (exp + relu^2) packed in-register, sibling halves exchanged via 16KB pex,
// dual-accumulator PV (24 MFMA, V-frag shared), lane-local lsum, counted
// vmcnt staging. LDS 64KB, launch_bounds(256,2), 2 blocks/CU.
// ---------------------------------------------------------------------------
__global__ __launch_bounds__(256, 2) void attn_fused(
    const u16* __restrict__ qb, const u16* __restrict__ kb,
    const u16* __restrict__ vtb, const float* __restrict__ w1p,
    const float* __restrict__ w2p, const float* __restrict__ x,
    float* __restrict__ out) {
  __shared__ u16 sm[32768];   // K@0 24KB | V^T@12288 24KB | pexS@24576 8KB | pexR@28672 8KB
  float* olds = (float*)sm;   // epilogue overlay [192][64] f32 (48KB)
  float* lred = (float*)(sm + 24576);  // epilogue lsum exchange

  int t = threadIdx.x, w = t >> 6, lane = t & 63;
  int l31 = lane & 31, hi = lane >> 5;
  int qh = w >> 1, ch = w & 1;
  int bid = blockIdx.x;
  int xcd = bid & 7, j = bid >> 3;
  int b = xcd * 2 + (j >= 36 ? 1 : 0);
  int qt = (j >= 36) ? j - 36 : j;

  const u16* Kg = kb + (size_t)b * NN * CC;
  const u16* Vg = vtb + (size_t)b * CC * NN;
  const u16* Qr = qb + ((size_t)b * NN + qt * 64 + qh * 32 + l31) * CC + hi * 8;
  bf16x8 qf[12];
#pragma unroll
  for (int ks = 0; ks < 12; ++ks) qf[ks] = *(const bf16x8*)(Qr + ks * 16);

  float e1 = __expf(w1p[0]), e2 = __expf(w2p[0]);
  float den = e1 + e2;
  float c1f = e1 / den, c2f = e2 / den;

  // P-frag exchange: per owner-wave region of 2 frags x 64 lanes x 16B (2KB)
  u16* pexSW = sm + 24576 + (qh * 2 + ch) * 1024 + lane * 8;
  const u16* pexSR = sm + 24576 + (qh * 2 + (1 - ch)) * 1024 + lane * 8;
  u16* pexRW = sm + 28672 + (qh * 2 + ch) * 1024 + lane * 8;
  const u16* pexRR = sm + 28672 + (qh * 2 + (1 - ch)) * 1024 + lane * 8;

  f32x16 z16;
#pragma unroll
  for (int i = 0; i < 16; ++i) z16[i] = 0.f;
  f32x16 os[3], orl[3];
#pragma unroll
  for (int i = 0; i < 3; ++i) { os[i] = z16; orl[i] = z16; }
  float lsum = 0.f;

#define STAGE_K(KT)                                                        \
  {                                                                        \
    _Pragma("unroll") for (int i = 0; i < 6; ++i) {                        \
      int cid = i * 4 + w, sc = cid * 64 + lane;                           \
      int row = sc / 24, pc = sc % 24;                                     \
      int gc = (pc & ~7) | ((pc ^ row) & 7);                               \
      gll16(Kg + ((size_t)(KT) * 64 + row) * CC + gc * 8, sm + cid * 512); \
    }                                                                      \
  }
#define STAGE_V(KT)                                                        \
  {                                                                        \
    _Pragma("unroll") for (int i = 0; i < 6; ++i) {                        \
      int cid = i * 4 + w, sc = cid * 64 + lane;                           \
      int d = sc >> 3, pc = sc & 7, gc = (pc ^ d) & 7;                     \
      gll16(Vg + (size_t)d * NN + (KT) * 64 + gc * 8,                      \
            sm + 12288 + cid * 512);                                       \
    }                                                                      \
  }

  alignas(16) uint32_t pS0[4], pS1[4], pR0[4], pR1[4];
  // S(kt) for own k-half -> exp & relu^2 packed to TWO A-frag sets; lsum accum
#define S_BLEND()                                                           \
  {                                                                         \
    f32x16 sA0 = z16, sA1 = z16;                                            \
    __builtin_amdgcn_s_setprio(1);                                          \
    _Pragma("unroll") for (int ks = 0; ks < 6; ++ks) {                      \
      bf16x8 k0 =                                                           \
          *(const bf16x8*)&sm[swzK(ch * 32 + l31, (2 * ks) * 16 + hi * 8)]; \
      bf16x8 k1 =                                                           \
          *(const bf16x8*)&sm[swzK(ch * 32 + l31, (2 * ks + 1) * 16 + hi * 8)]; \
      sA0 = __builtin_amdgcn_mfma_f32_32x32x16_bf16(k0, qf[2 * ks], sA0, 0, 0, 0); \
      sA1 = __builtin_amdgcn_mfma_f32_32x32x16_bf16(k1, qf[2 * ks + 1], sA1, 0, 0, 0); \
    }                                                                       \
    __builtin_amdgcn_s_setprio(0);                                          \
    uint32_t WS[8], WR[8];                                                  \
    _Pragma("unroll") for (int g = 0; g < 4; ++g) {                         \
      float sv0 = sA0[4 * g + 0] + sA1[4 * g + 0];                          \
      float sv1 = sA0[4 * g + 1] + sA1[4 * g + 1];                          \
      float sv2 = sA0[4 * g + 2] + sA1[4 * g + 2];                          \
      float sv3 = sA0[4 * g + 3] + sA1[4 * g + 3];                          \
      float e0 = __expf(fminf(sv0, 60.f));                                  \
      float e1v = __expf(fminf(sv1, 60.f));                                 \
      float e2v = __expf(fminf(sv2, 60.f));                                 \
      float e3 = __expf(fminf(sv3, 60.f));                                  \
      float r0 = fmaxf(sv0, 0.f), r1 = fmaxf(sv1, 0.f);                     \
      float r2 = fmaxf(sv2, 0.f), r3 = fmaxf(sv3, 0.f);                     \
      lsum += (e0 + e1v) + (e2v + e3);                                      \
      WS[2 * g] = cvtpk(e0, e1v);                                           \
      WS[2 * g + 1] = cvtpk(e2v, e3);                                       \
      WR[2 * g] = cvtpk(r0 * r0, r1 * r1);                                  \
      WR[2 * g + 1] = cvtpk(r2 * r2, r3 * r3);                              \
    }                                                                       \
    uint32_t XS[8], XR[8];                                                  \
    _Pragma("unroll") for (int jj = 0; jj < 8; ++jj) {                      \
      XS[jj] = __shfl_xor(WS[jj], 32);                                      \
      XR[jj] = __shfl_xor(WR[jj], 32);                                      \
    }                                                                       \
    pS0[0] = hi ? XS[2] : WS[0]; pS0[1] = hi ? XS[3] : WS[1];               \
    pS0[2] = hi ? WS[2] : XS[0]; pS0[3] = hi ? WS[3] : XS[1];               \
    pS1[0] = hi ? XS[6] : WS[4]; pS1[1] = hi ? XS[7] : WS[5];               \
    pS1[2] = hi ? WS[6] : XS[4]; pS1[3] = hi ? WS[7] : XS[5];               \
    pR0[0] = hi ? XR[2] : WR[0]; pR0[1] = hi ? XR[3] : WR[1];               \
    pR0[2] = hi ? WR[2] : XR[0]; pR0[3] = hi ? WR[3] : XR[1];               \
    pR1[0] = hi ? XR[6] : WR[4]; pR1[1] = hi ? XR[7] : WR[5];               \
    pR1[2] = hi ? WR[6] : XR[4]; pR1[3] = hi ? WR[7] : XR[5];               \
    *(uint4*)pexSW = *(uint4*)pS0;                                          \
    *(uint4*)(pexSW + 512) = *(uint4*)pS1;                                  \
    *(uint4*)pexRW = *(uint4*)pR0;                                          \
    *(uint4*)(pexRW + 512) = *(uint4*)pR1;                                  \
  }

  // ---- prologue: K(0)+V(0) in flight; S(0) -> frags; issue K(1) ----
  STAGE_K(0);
  STAGE_V(0);
  asm volatile("s_waitcnt vmcnt(6)\ns_barrier" ::: "memory");   // K(0) landed
  S_BLEND();
  asm volatile("s_waitcnt lgkmcnt(0)\ns_barrier" ::: "memory"); // S reads + pex pub
  STAGE_K(1);

  for (int kt = 0; kt < 36; ++kt) {
    // A: V(kt) landed (6 newer K glls stay in flight)
    if (kt == 35)
      asm volatile("s_waitcnt vmcnt(0) lgkmcnt(0)\ns_barrier" ::: "memory");
    else
      asm volatile("s_waitcnt vmcnt(6) lgkmcnt(0)\ns_barrier" ::: "memory");

    // ---- PV(kt): os/orl += P @ V; own frags regs, sibling via pex ----
    const u16* vl = sm + 12288;
    uint4 sS0 = *(const uint4*)pexSR;
    uint4 sS1 = *(const uint4*)(pexSR + 512);
    uint4 sR0 = *(const uint4*)pexRR;
    uint4 sR1 = *(const uint4*)(pexRR + 512);
    __builtin_amdgcn_s_setprio(1);
#pragma unroll
    for (int dt = 0; dt < 3; ++dt) {
      int d = ch * 96 + dt * 32 + l31;
      bf16x8 vo0 = *(const bf16x8*)&vl[swz64(d, (ch * 2 + 0) * 16 + hi * 8)];
      bf16x8 vo1 = *(const bf16x8*)&vl[swz64(d, (ch * 2 + 1) * 16 + hi * 8)];
      bf16x8 vs0 = *(const bf16x8*)&vl[swz64(d, ((1 - ch) * 2 + 0) * 16 + hi * 8)];
      bf16x8 vs1 = *(const bf16x8*)&vl[swz64(d, ((1 - ch) * 2 + 1) * 16 + hi * 8)];
      os[dt] = __builtin_amdgcn_mfma_f32_32x32x16_bf16(
          *(const bf16x8*)pS0, vo0, os[dt], 0, 0, 0);
      orl[dt] = __builtin_amdgcn_mfma_f32_32x32x16_bf16(
          *(const bf16x8*)pR0, vo0, orl[dt], 0, 0, 0);
      os[dt] = __builtin_amdgcn_mfma_f32_32x32x16_bf16(
          *(const bf16x8*)pS1, vo1, os[dt], 0, 0, 0);
      orl[dt] = __builtin_amdgcn_mfma_f32_32x32x16_bf16(
          *(const bf16x8*)pR1, vo1, orl[dt], 0, 0, 0);
      os[dt] = __builtin_amdgcn_mfma_f32_32x32x16_bf16(
          *(const bf16x8*)&sS0, vs0, os[dt], 0, 0, 0);
      orl[dt] = __builtin_amdgcn_mfma_f32_32x32x16_bf16(
          *(const bf16x8*)&sR0, vs0, orl[dt], 0, 0, 0);
      os[dt] = __builtin_amdgcn_mfma_f32_32x32x16_bf16(
          *(const bf16x8*)&sS1, vs1, os[dt], 0, 0, 0);
      orl[dt] = __builtin_amdgcn_mfma_f32_32x32x16_bf16(
          *(const bf16x8*)&sR1, vs1, orl[dt], 0, 0, 0);
    }
    __builtin_amdgcn_s_setprio(0);

    if (kt < 35) {
      // BC: PV + pex reads done; K(kt+1) landed (only outstanding glls)
      asm volatile("s_waitcnt vmcnt(0) lgkmcnt(0)\ns_barrier" ::: "memory");
      STAGE_V(kt + 1);           // flies under S(kt+1) + next A
      S_BLEND();                 // S(kt+1) -> frags (P for next PV)
      // D: S reads done + pex writes drained -> K region free, pex published
      asm volatile("s_waitcnt lgkmcnt(0)\ns_barrier" ::: "memory");
      if (kt + 2 < 36) STAGE_K(kt + 2);  // flies under PV(kt+1)
    }
  }

  // ---- epilogue: reduce lsum, blend, transpose, residual add, store ----
  lsum += __shfl_xor(lsum, 32);           // fold hi-half partner
  __syncthreads();                        // loop LDS traffic complete
  if (lane < 32) lred[(qh * 2 + ch) * 32 + l31] = lsum;
  __syncthreads();
  float linv[16];
#pragma unroll
  for (int r = 0; r < 16; ++r) {
    int m = (r & 3) + 8 * (r >> 2) + 4 * hi;
    float ltot = lred[(qh * 2 + 0) * 32 + m] + lred[(qh * 2 + 1) * 32 + m];
    linv[r] = c1f / ltot;
  }
  __syncthreads();                        // lred reads done before olds overlay
#pragma unroll
  for (int dt = 0; dt < 3; ++dt) {
    int d = ch * 96 + dt * 32 + l31;
#pragma unroll
    for (int r = 0; r < 16; ++r) {
      int m = (r & 3) + 8 * (r >> 2) + 4 * hi;
      int q = qh * 32 + m;
      olds[d * 64 + ((q & ~31) | ((q ^ d) & 31))] =
          os[dt][r] * linv[r] + c2f * orl[dt][r];
    }
  }
  __syncthreads();
  const float* xb = x + (size_t)b * CC * NN + qt * 64;
  float* ob = out + (size_t)b * CC * NN + qt * 64;
#pragma unroll
  for (int i = 0; i < 48; ++i) {
    int idx = i * 256 + t;
    int c = idx >> 6, nn = idx & 63;
    float v = olds[c * 64 + ((nn & ~31) | ((nn ^ c) & 31))];
    ob[(size_t)c * NN + nn] = v + xb[(size_t)c * NN + nn];
  }
#undef STAGE_K
#undef STAGE_V
#undef S_BLEND
}

// ---------------------------------------------------------------------------
extern "C" void kernel_launch(void* const* d_in, const int* in_sizes, int n_in,
                              void* d_out, int out_size, void* d_ws, size_t ws_size,
                              hipStream_t stream) {
  (void)in_sizes; (void)n_in; (void)out_size; (void)ws_size;
  const float* x   = (const float*)d_in[0];
  const float* lnw = (const float*)d_in[1];
  const float* lnb = (const float*)d_in[2];
  const float* Wq  = (const float*)d_in[3];
  const float* Wk  = (const float*)d_in[4];
  const float* Wv  = (const float*)d_in[5];
  const float* w1  = (const float*)d_in[6];
  const float* w2  = (const float*)d_in[7];
  float* out = (float*)d_out;

  u16* xn = (u16*)d_ws;
  size_t per = (size_t)NBATCH * NN * CC;
  u16* qb  = xn + per;
  u16* kb  = qb + per;
  u16* vtb = kb + per;
  u16* wbf = vtb + per;   // 3*192*192 bf16 = 221 KB

  ln_kernel<<<dim3(36, 16), 256, 0, stream>>>(x, lnw, lnb, xn);
  wconv_kernel<<<dim3(18, 3), 256, 0, stream>>>(Wq, Wk, Wv, wbf);
  qkv_gemm<<<dim3(576, 3), 256, 0, stream>>>(xn, wbf, qb, kb, vtb);
  attn_fused<<<dim3(576), 256, 0, stream>>>(qb, kb, vtb, w1, w2, x, out);
}